// Round 9
// baseline (42.903 us; speedup 1.0000x reference)
//
#include <hip/hip_runtime.h>

// B=64, H=W=512, K=7, VALID conv -> 506x506.
// v9: LDS-free direct conv (v8 structure) + 4-col x 8-row register micro-tile.
// Per input row each thread loads float4+float4+float2 (10 floats = all taps
// for 4 outputs): VMEM instrs/thread 98 -> 42, per-output L1 bytes ~5x down.
// No __launch_bounds__ 2nd arg (v3/v4/v7 spill catastrophes).
#define HW 512
#define OW 506

__global__ __launch_bounds__(256) void conv7x7_v9(
    const float* __restrict__ in,      // [64][512][512]
    const float* __restrict__ weight,  // [7][7]
    const float* __restrict__ bias,    // [1]
    float* __restrict__ out)           // [64][506][506]
{
    const int tid  = threadIdx.x;
    const int lane = tid & 63;
    const int w    = tid >> 6;
    const int x0   = blockIdx.x * 256;          // 64 lanes x 4 cols
    const int yb   = blockIdx.y * 32 + w * 8;   // wave's first output row
    const int b    = blockIdx.z;

    // ---- weights + bias -> SGPRs (uniform, statically indexed) ----
    float wv[49];
#pragma unroll
    for (int i = 0; i < 49; ++i)
        wv[i] = __uint_as_float(__builtin_amdgcn_readfirstlane(__float_as_uint(weight[i])));
    const float bv = __uint_as_float(__builtin_amdgcn_readfirstlane(__float_as_uint(bias[0])));

    const float* __restrict__ ib = in + (size_t)b * (HW * HW);

    // output cols cb..cb+3; load bases clamped so all vector loads stay
    // inside the row. Clamped lanes' garbage only feeds guarded outputs:
    //  - cbl<cb only when cb=508 (all 4 outputs >=506, never stored)
    //  - c2b<cb+8 only when cb>=504 (f10[8..9] feed outputs cb+2,cb+3 >=506)
    const int cb  = x0 + 4 * lane;
    const int cbl = min(cb, HW - 8);        // float4 pair base (16B aligned)
    const int c2b = min(cb + 8, HW - 2);    // float2 base (8B aligned)

    float acc[32];
#pragma unroll
    for (int i = 0; i < 32; ++i) acc[i] = 0.f;

    // 14 input rows feed 8 output rows x 4 cols.
#pragma unroll
    for (int ir = 0; ir < 14; ++ir) {
        const int row = min(yb + ir, HW - 1);      // wave-uniform clamp
        const float* p = ib + row * HW;
        const float4 q0 = *reinterpret_cast<const float4*>(p + cbl);
        const float4 q1 = *reinterpret_cast<const float4*>(p + cbl + 4);
        const float2 c2 = *reinterpret_cast<const float2*>(p + c2b);
        const float f10[10] = {q0.x, q0.y, q0.z, q0.w,
                               q1.x, q1.y, q1.z, q1.w,
                               c2.x, c2.y};

#pragma unroll
        for (int kr = 0; kr < 7; ++kr) {
            const int s = ir - kr;                 // compile-time after unroll
            if (s >= 0 && s < 8) {
#pragma unroll
                for (int kc = 0; kc < 7; ++kc) {
                    const float wk = wv[kr * 7 + kc];
#pragma unroll
                    for (int j = 0; j < 4; ++j)
                        acc[s * 4 + j] = fmaf(wk, f10[kc + j], acc[s * 4 + j]);
                }
            }
        }
    }

    // ---- store: 4 cols as two float2 (8B-aligned: oy*506 and cb both even) ----
    float* __restrict__ outb = out + (size_t)b * (OW * OW);
#pragma unroll
    for (int s = 0; s < 8; ++s) {
        const int oy = yb + s;
        if (oy < OW) {
            float* orow = outb + (size_t)oy * OW + cb;
            if (cb + 1 < OW)
                *reinterpret_cast<float2*>(orow) =
                    make_float2(acc[s * 4 + 0] + bv, acc[s * 4 + 1] + bv);
            if (cb + 3 < OW)
                *reinterpret_cast<float2*>(orow + 2) =
                    make_float2(acc[s * 4 + 2] + bv, acc[s * 4 + 3] + bv);
        }
    }
}

extern "C" void kernel_launch(void* const* d_in, const int* in_sizes, int n_in,
                              void* d_out, int out_size, void* d_ws, size_t ws_size,
                              hipStream_t stream) {
    const float* enc_x  = (const float*)d_in[0];
    const float* weight = (const float*)d_in[1];
    const float* bias   = (const float*)d_in[2];
    float* outp         = (float*)d_out;

    // 2 x 256 cols, 16 x 32 rows, 64 images = 2048 blocks = 8/CU co-resident.
    dim3 grid(2, 16, 64);
    dim3 block(256);
    hipLaunchKernelGGL(conv7x7_v9, grid, block, 0, stream,
                       enc_x, weight, bias, outp);
}